// Round 7
// baseline (298.183 us; speedup 1.0000x reference)
//
#include <hip/hip_runtime.h>
#include <hip/hip_bf16.h>

// MHA forward. B=4, T=2048, D=1024, H=16, Hd=64. Inputs auto-detected f32/bf16.
// convert x -> fused convert+transpose weights -> QKV GEMM (256x256 4-phase
// m201-style, +bias; Q pre-scaled by log2e/8; V written transposed to vT
// in-epilogue) -> flash attention v12 -> out GEMM(+bias, 128^2 dbuf).
// R4: never cap occupancy via __launch_bounds__ 2nd arg (spill disaster).
// R5: don't interleave P LDS writes into PV chain. R6: keep S live range to one kb.
// R7: all single-buffer variants stall ~120us on per-tile barrier drain.
// R8: v8 latency-bound at 2 waves/SIMD; v9 512-thr 32q/wave -> 4 waves/SIMD (101us).
// R9: v10 manual pipeline+stagger+setprio REGRESSED (127us): manual ordering
//     defeats compiler sched (m141); barrier re-syncs waves, stagger can't help.
// R10: v11 no-LDS direct-global attention REGRESSED 3.5x: K-row stride 6KB ->
//     L1/TA issue serializes. LDS staging IS the coalescer. Keep LDS form.
// R12: lp-as-f32x4 REGRESSED 101->114us: acc vectorization perturbed regalloc.
// R14: 256^2 4-phase gemm1 port = neutral: 384 blocks @ 1 block/CU = 1.5 dispatch
//     rounds -> 75% quantization. Tail structurally unfixable (2 blocks/CU needs
//     VGPR<=128 but acc[8][4]=128 alone). Alternative tiles trade tail for worse
//     ds:MFMA ratio (~net 0). gemm1 accepted as-is.
// R15 (this round): attention is issue-slot-bound (VALU 45.9 + MFMA 43.7 = 89%,
//     VALU the longer pole). Move softmax denominator to the MFMA pipe:
//     lsum = MFMA(ones, P, lsum) -> row-sum replicated across rows; epilogue
//     reads lsum[0], shuffles deleted. -128 VALU-cy +64 MFMA-cy per wave-tile.
//     Also: fuse 2 transpose launches into 1; fold bias-conv into sniff (8->6
//     launches).

typedef __bf16 bf16_t;
typedef __bf16 bf16x8 __attribute__((ext_vector_type(8)));
typedef float f32x4 __attribute__((ext_vector_type(4)));
typedef short short4v __attribute__((ext_vector_type(4)));

#if __has_builtin(__builtin_amdgcn_mfma_f32_16x16x16_bf16)
typedef __bf16 bf16x4 __attribute__((ext_vector_type(4)));
#define MFMA_PV(va, vb, c) __builtin_amdgcn_mfma_f32_16x16x16_bf16( \
    __builtin_bit_cast(bf16x4, (va)), __builtin_bit_cast(bf16x4, (vb)), (c), 0, 0, 0)
#else
#define MFMA_PV(va, vb, c) __builtin_amdgcn_mfma_f32_16x16x16bf16_1k((va), (vb), (c), 0, 0, 0)
#endif

#define DMODEL 1024
#define NH     16
#define HD     64
#define BATCH  4
#define SEQ    2048
#define NTOK   (BATCH * SEQ)      // 8192
#define NOUT   (NTOK * DMODEL)    // 8388608
#define CEXP   0.1803368801111204f   // log2(e)/sqrt(64)

__device__ __forceinline__ void async_ld16(void* lds, const void* g) {
  __builtin_amdgcn_global_load_lds(
      (const __attribute__((address_space(1))) void*)g,
      (__attribute__((address_space(3))) void*)lds, 16, 0, 0);
}

// ------------------------------------------------------------- dtype sniff + biases
// 8192 u16 samples via vectorized loads; f32 data -> ~32 NaN-pattern low halves.
// After the in-block flag reduction, the same block converts both bias vectors
// (4096 elems, 16 iters x 256 lanes) using the locally-known flag -> one launch
// replaces two, and the bias path needs no global flag round-trip.
__global__ __launch_bounds__(256) void sniff_dtype(
    const uint4* __restrict__ x, int* __restrict__ flag,
    const void* __restrict__ sq, const void* __restrict__ so,
    float* __restrict__ dq, float* __restrict__ dofs) {
  int t = threadIdx.x;
  int nanish = 0, zc = 0;
  for (int j = 0; j < 4; ++j) {
    uint4 w = x[t + j * 256];
    unsigned u[4] = {w.x, w.y, w.z, w.w};
    for (int k = 0; k < 4; ++k) {
      unsigned lo = u[k] & 0xFFFFu, hi = u[k] >> 16;
      if ((lo & 0x7F80u) == 0x7F80u) nanish++;
      if ((hi & 0x7F80u) == 0x7F80u) nanish++;
      if (lo == 0) zc++;
      if (hi == 0) zc++;
    }
  }
  __shared__ int rn[256], rz[256];
  rn[t] = nanish; rz[t] = zc;
  __syncthreads();
  for (int s = 128; s > 0; s >>= 1) {
    if (t < s) { rn[t] += rn[t + s]; rz[t] += rz[t + s]; }
    __syncthreads();
  }
  const int f = (rn[0] > 4 || rz[0] > 2048) ? 1 : 0;   // 1 = f32 inputs
  if (t == 0) flag[0] = f;
  for (int j = 0; j < 16; ++j) {
    int i = j * 256 + t;                               // 0..4095
    if (i < 3072)
      dq[i] = f ? ((const float*)sq)[i] : (float)((const bf16_t*)sq)[i];
    else {
      int k = i - 3072;
      dofs[k] = f ? ((const float*)so)[k] : (float)((const bf16_t*)so)[k];
    }
  }
}

// ------------------------------------------------------------- converter
__global__ __launch_bounds__(256) void conv_to_bf16(
    const void* __restrict__ src, bf16_t* __restrict__ dst, int n,
    const int* __restrict__ flag) {
  int i = (blockIdx.x * 256 + threadIdx.x) * 8;
  if (i >= n) return;
  if (flag[0]) {
    const float4* s = (const float4*)((const float*)src + i);
    float4 a = s[0], b = s[1];
    bf16_t* o = dst + i;
    o[0] = (bf16_t)a.x; o[1] = (bf16_t)a.y; o[2] = (bf16_t)a.z; o[3] = (bf16_t)a.w;
    o[4] = (bf16_t)b.x; o[5] = (bf16_t)b.y; o[6] = (bf16_t)b.z; o[7] = (bf16_t)b.w;
  } else {
    *(uint4*)(dst + i) = *(const uint4*)((const bf16_t*)src + i);
  }
}

// ------------------------------------------------------------- weight transpose (fused)
// bx < 96: w_qkv (1024 x 3072) -> wqkvT. bx >= 96: w_out (1024 x 1024) -> woutT.
__global__ __launch_bounds__(256) void transpose_w2(
    const void* __restrict__ in0, bf16_t* __restrict__ out0,
    const void* __restrict__ in1, bf16_t* __restrict__ out1,
    const int* __restrict__ flag) {
  __shared__ bf16_t tile[32][33];
  const int tx = threadIdx.x & 31, ty = threadIdx.x >> 5;
  const bool second = blockIdx.x >= 96;
  const void* in = second ? in1 : in0;
  bf16_t* out = second ? out1 : out0;
  const int C = second ? 1024 : 3072;
  const int R = 1024;
  const int c0 = (second ? (blockIdx.x - 96) : blockIdx.x) * 32;
  const int r0 = blockIdx.y * 32;
  if (flag[0]) {
    for (int i = 0; i < 4; ++i) {
      int r = ty + i * 8;
      tile[r][tx] = (bf16_t)((const float*)in)[(size_t)(r0 + r) * C + c0 + tx];
    }
  } else {
    for (int i = 0; i < 4; ++i) {
      int r = ty + i * 8;
      tile[r][tx] = ((const bf16_t*)in)[(size_t)(r0 + r) * C + c0 + tx];
    }
  }
  __syncthreads();
  for (int i = 0; i < 4; ++i) {
    int r = ty + i * 8;
    out[(size_t)(c0 + r) * R + r0 + tx] = tile[tx][r];
  }
}

// ------------------------------------------------------------- 128^2 GEMM (B^T) + bias
// MODE 1 only (out-proj): dyn f32/bf16 per flag. 2-phase dbuf, counted vmcnt.
template <int MODE>
__global__ __launch_bounds__(256) void gemm_bt_bias(
    const bf16_t* __restrict__ A, const bf16_t* __restrict__ Bt,
    const float* __restrict__ bias, void* __restrict__ Cout,
    int M, int N, int K, const int* __restrict__ flag) {
  __shared__ bf16_t sA[2][128 * 32];
  __shared__ bf16_t sB[2][128 * 32];
  const int t = threadIdx.x;
  const int wave = t >> 6, lane = t & 63;
  const int quad = lane >> 4, l16 = lane & 15;
  const int nwg = gridDim.x * gridDim.y;
  const int lin = blockIdx.y * gridDim.x + blockIdx.x;
  const int cpx = nwg >> 3;                    // nwg % 8 == 0 for our grids
  const int swz = (lin & 7) * cpx + (lin >> 3);
  const int bx = swz % gridDim.x, by = swz / gridDim.x;
  const int bM = by * 128, bN = bx * 128;
  const int m0w = (wave >> 1) * 64, n0w = (wave & 1) * 64;
  const int rowS = wave * 16 + (lane >> 2);
  const int kcS = (lane & 3) * 8;

  f32x4 acc[4][4] = {};

  auto stage = [&](int buf, int k0) {
    for (int r = 0; r < 2; ++r) {
      int row = r * 64 + rowS;
      async_ld16((char*)sA[buf] + r * 4096 + wave * 1024,
                 A + (size_t)(bM + row) * K + k0 + kcS);
      async_ld16((char*)sB[buf] + r * 4096 + wave * 1024,
                 Bt + (size_t)(bN + row) * K + k0 + kcS);
    }
  };

  const int nsteps = K >> 5;
  stage(0, 0);

  for (int s = 0; s < nsteps; ++s) {
    const int cur = s & 1;
    if (s + 1 < nsteps) {
      stage(cur ^ 1, (s + 1) << 5);
      asm volatile("s_waitcnt vmcnt(4)" ::: "memory");
    } else {
      asm volatile("s_waitcnt vmcnt(0)" ::: "memory");
    }
    __builtin_amdgcn_s_barrier();
    asm volatile("" ::: "memory");

    bf16x8 af[4], bfr[4];
    for (int i = 0; i < 4; ++i)
      af[i] = *(const bf16x8*)&sA[cur][(m0w + i * 16 + l16) * 32 + quad * 8];
    for (int j = 0; j < 4; ++j)
      bfr[j] = *(const bf16x8*)&sB[cur][(n0w + j * 16 + l16) * 32 + quad * 8];
    for (int i = 0; i < 4; ++i)
      for (int j = 0; j < 4; ++j)
        acc[i][j] = __builtin_amdgcn_mfma_f32_16x16x32_bf16(af[i], bfr[j], acc[i][j], 0, 0, 0);

    asm volatile("" ::: "memory");
    __builtin_amdgcn_s_barrier();
  }

  const bool f32out = (MODE == 1) && flag[0];
  for (int j = 0; j < 4; ++j) {
    int col = bN + n0w + j * 16 + l16;
    float bv = bias[col];
    for (int i = 0; i < 4; ++i) {
      int row0 = bM + m0w + i * 16 + quad * 4;
      for (int r = 0; r < 4; ++r) {
        float v = acc[i][j][r] + bv;
        if (f32out) ((float*)Cout)[(size_t)(row0 + r) * N + col] = v;
        else        ((bf16_t*)Cout)[(size_t)(row0 + r) * N + col] = (bf16_t)v;
      }
    }
  }
}

// ------------------------------------------------------------- 256^2 4-phase QKV GEMM
// (verified R6; see R14 note). 512 thr = 8 waves (2M x 4N); acc[8][4] per wave.
// K-tile BK=64 = 4 LDS units [256 rows][32 k]: U0=(A,k0) U1=(B,k0) U2=(A,k1)
// U3=(B,k1). 2-tile dbuf = 128KB. Swizzle byte ^= ((row&8)<<1)|((row&4)<<3);
// gload_lds linear dest + pre-inverse-swizzled source. 1 counted vmcnt(4)/tile;
// each unit staged one phase after the barrier retiring its readers.
__global__ __launch_bounds__(512) void gemm256_qkv(
    const bf16_t* __restrict__ A, const bf16_t* __restrict__ Bt,
    const float* __restrict__ bias, bf16_t* __restrict__ Cout,
    int M, int N, int K, bf16_t* __restrict__ vT) {
  __shared__ __align__(16) char smem[131072];
  char* lds = smem;
  const int t = threadIdx.x;
  const int wave = t >> 6, lane = t & 63;
  const int quad = lane >> 4, l16 = lane & 15;
  const int wr = wave >> 2, wc = wave & 3;
  const int nwg = gridDim.x * gridDim.y;       // 384, %8==0
  const int lin = blockIdx.y * gridDim.x + blockIdx.x;
  const int cpx = nwg >> 3;
  const int swzb = (lin & 7) * cpx + (lin >> 3);
  const int bx = swzb % gridDim.x, by = swzb / gridDim.x;
  const int bM = by * 256, bN = bx * 256;

  const int srow = t >> 2;
  const int xr = ((srow >> 3) & 1) | (((srow >> 2) & 1) << 1);
  const int skl = ((t ^ xr) & 3) * 8;
  const size_t offA0 = (size_t)(bM + srow) * K + skl;
  const size_t offB0 = (size_t)(bN + srow) * K + skl;
  const size_t off1 = (size_t)128 * K;
  const int ldsw = wave * 1024;

#define STG_A(bufo, h, k0t) do {                                               \
    async_ld16(lds + (bufo) + (h) * 16384 + ldsw, A + offA0 + (k0t) + (h) * 32);\
    async_ld16(lds + (bufo) + (h) * 16384 + 8192 + ldsw,                       \
               A + offA0 + off1 + (k0t) + (h) * 32); } while (0)
#define STG_B(bufo, h, k0t) do {                                               \
    async_ld16(lds + (bufo) + 32768 + (h) * 16384 + ldsw,                      \
               Bt + offB0 + (k0t) + (h) * 32);                                 \
    async_ld16(lds + (bufo) + 32768 + (h) * 16384 + 8192 + ldsw,               \
               Bt + offB0 + off1 + (k0t) + (h) * 32); } while (0)

  int aoff[8], boff[4];
#pragma unroll
  for (int mf = 0; mf < 8; ++mf) {
    int r = wr * 128 + mf * 16 + l16;
    aoff[mf] = ((r << 6) + (quad << 4)) ^ (((r & 8) << 1) | ((r & 4) << 3));
  }
#pragma unroll
  for (int nf = 0; nf < 4; ++nf) {
    int r = wc * 64 + nf * 16 + l16;
    boff[nf] = 32768 + (((r << 6) + (quad << 4)) ^ (((r & 8) << 1) | ((r & 4) << 3)));
  }

  f32x4 acc[8][4] = {};
  bf16x8 af[4], bf[4];

#define LDA_SET(mfb, h, bufo) do {                                             \
    af[0] = *(const bf16x8*)(lds + (bufo) + (h) * 16384 + aoff[(mfb) + 0]);    \
    af[1] = *(const bf16x8*)(lds + (bufo) + (h) * 16384 + aoff[(mfb) + 1]);    \
    af[2] = *(const bf16x8*)(lds + (bufo) + (h) * 16384 + aoff[(mfb) + 2]);    \
    af[3] = *(const bf16x8*)(lds + (bufo) + (h) * 16384 + aoff[(mfb) + 3]); } while (0)
#define LDB_SET(h, bufo) do {                                                  \
    bf[0] = *(const bf16x8*)(lds + (bufo) + (h) * 16384 + boff[0]);            \
    bf[1] = *(const bf16x8*)(lds + (bufo) + (h) * 16384 + boff[1]);            \
    bf[2] = *(const bf16x8*)(lds + (bufo) + (h) * 16384 + boff[2]);            \
    bf[3] = *(const bf16x8*)(lds + (bufo) + (h) * 16384 + boff[3]); } while (0)
#define MFMA16(mfb) do {                                                       \
    _Pragma("unroll") for (int i_ = 0; i_ < 4; ++i_)                           \
      { _Pragma("unroll") for (int j_ = 0; j_ < 4; ++j_)                       \
        acc[(mfb) + i_][j_] = __builtin_amdgcn_mfma_f32_16x16x32_bf16(         \
            af[i_], bf[j_], acc[(mfb) + i_][j_], 0, 0, 0); } } while (0)
#define BAR1() do { __builtin_amdgcn_s_barrier(); asm volatile("" ::: "memory"); \
    __builtin_amdgcn_s_setprio(1); } while (0)
#define BAR2() do { __builtin_amdgcn_s_setprio(0);                             \
    asm volatile("" ::: "memory"); __builtin_amdgcn_s_barrier(); } while (0)

  const int NT = K >> 6;                       // 16
  STG_A(0, 0, 0); STG_B(0, 0, 0); STG_A(0, 1, 0); STG_B(0, 1, 0);
  STG_A(65536, 0, 64); STG_B(65536, 0, 64);
  asm volatile("s_waitcnt vmcnt(4)" ::: "memory");
  __builtin_amdgcn_s_barrier();
  asm volatile("" ::: "memory");

  for (int T = 0; T < NT; ++T) {
    const int bufo = (T & 1) << 16;
    const int obufo = bufo ^ 65536;
    const int k1 = (T + 1) << 6, k2 = (T + 2) << 6;
    LDA_SET(0, 0, bufo); LDB_SET(0, bufo);
    if (T + 1 < NT) STG_A(obufo, 1, k1);
    BAR1(); MFMA16(0); BAR2();
    LDA_SET(4, 0, bufo);
    if (T + 1 < NT) STG_B(obufo, 1, k1);
    BAR1(); MFMA16(4); BAR2();
    LDA_SET(0, 1, bufo); LDB_SET(1, bufo);
    if (T + 2 < NT) STG_A(bufo, 0, k2);
    BAR1(); MFMA16(0); BAR2();
    LDA_SET(4, 1, bufo);
    if (T + 2 < NT) {
      STG_B(bufo, 0, k2);
      asm volatile("s_waitcnt vmcnt(4)" ::: "memory");
    } else {
      asm volatile("s_waitcnt vmcnt(0)" ::: "memory");
    }
    BAR1(); MFMA16(4); BAR2();
  }

#pragma unroll
  for (int nf = 0; nf < 4; ++nf) {
    int col = bN + wc * 64 + nf * 16 + l16;
    float bv = bias[col];
#pragma unroll
    for (int mf = 0; mf < 8; ++mf) {
      int row0 = bM + wr * 128 + mf * 16 + quad * 4;
      if (col >= 2048) {
        int hh = (col - 2048) >> 6, dd = (col - 2048) & 63;
        bf16_t o4[4];
        for (int r = 0; r < 4; ++r) o4[r] = (bf16_t)(acc[mf][nf][r] + bv);
        size_t dst = ((((size_t)(row0 >> 11) * NH + hh) * HD + dd) << 11) | (row0 & 2047);
        *(uint2*)&vT[dst] = *(uint2*)o4;
      } else {
        float scale = (col < 1024) ? CEXP : 1.0f;
        for (int r = 0; r < 4; ++r)
          Cout[(size_t)(row0 + r) * N + col] = (bf16_t)((acc[mf][nf][r] + bv) * scale);
      }
    }
  }
#undef STG_A
#undef STG_B
#undef LDA_SET
#undef LDB_SET
#undef MFMA16
#undef BAR1
#undef BAR2
}

// ------------------------------------------------------------- flash attention v12
// = v9 structure (verified 101us) with the softmax denominator moved to the MFMA
// pipe: lsum[s] = MFMA(ones, pB[s], lsum[s]) accumulates column sums of P (the
// per-q denominators, replicated across output rows) -> deletes 64 serial VALU
// adds per wave-tile AND the two epilogue __shfl_xor (l = lsum[s][0]).
// R12: no other accumulator-shape changes.
__global__ __launch_bounds__(512) void attention_v12(
    const bf16_t* __restrict__ qkv, const bf16_t* __restrict__ vT,
    bf16_t* __restrict__ attn) {
  const int t = threadIdx.x;
  const int wave = t >> 6, lane = t & 63;           // wave 0..7
  const int quad = lane >> 4, l16 = lane & 15;
  const int bh = blockIdx.x, b = bh >> 4, h = bh & 15;
  const int qw = blockIdx.y * 256 + wave * 32;

  __shared__ bf16_t Kt[2][128 * 64];   // [key][d], 16B-chunk XOR swizzle by key&7
  __shared__ bf16_t Vt[2][64 * 128];   // [d][key], 16B-chunk XOR swizzle by d&15

  const bf16_t* qglob = qkv + (size_t)b * SEQ * 3072 + h * 64;
  const bf16_t* kglob = qglob + 1024;
  const bf16_t* vglob = vT + (size_t)bh * HD * SEQ;

  bf16x8 qf[2][2];
  for (int s = 0; s < 2; ++s) {
    const bf16_t* qrow = qglob + (size_t)(qw + s * 16 + l16) * 3072 + quad * 8;
    qf[s][0] = *(const bf16x8*)qrow;
    qf[s][1] = *(const bf16x8*)(qrow + 32);
  }

  f32x4 accO[2][4] = {};
  f32x4 lsum[2] = {};                       // denominator via ones-MFMA
  const short4v ones4 = {(short)0x3F80, (short)0x3F80, (short)0x3F80, (short)0x3F80};

  const int kRow = lane >> 3, kSlot = lane & 7;
  const int vRow = lane >> 4, vSlot = lane & 15;

  auto stageKV = [&](int buf, int kt) {
    for (int j = 0; j < 2; ++j) {   // K: wave stages keys [wave*16, +16)
      int keyl = wave * 16 + j * 8 + kRow;
      int gc = kSlot ^ (keyl & 7);
      async_ld16((char*)Kt[buf] + (wave * 16 + j * 8) * 128,
                 kglob + (size_t)(kt + keyl) * 3072 + gc * 8);
    }
    for (int j = 0; j < 2; ++j) {   // V: wave stages d [wave*8, +8)
      int d = wave * 8 + j * 4 + vRow;
      int gc = vSlot ^ (d & 15);
      async_ld16((char*)Vt[buf] + (wave * 8 + j * 4) * 256,
                 vglob + (size_t)d * SEQ + kt + gc * 8);
    }
  };

  stageKV(0, 0);

  for (int ti = 0; ti < SEQ / 128; ++ti) {
    const int buf = ti & 1;
    __syncthreads();                       // drain this tile's DMA + publish
    if (ti + 1 < SEQ / 128) stageKV(buf ^ 1, (ti + 1) * 128);

    const bf16_t* KtB = Kt[buf];
    const bf16_t* VtB = Vt[buf];

    for (int kb = 0; kb < 8; ++kb) {
      const bf16_t* kr = &KtB[(kb * 16 + l16) * 64];
      bf16x8 kf0 = *(const bf16x8*)(kr + ((quad ^ (l16 & 7)) * 8));
      bf16x8 kf1 = *(const bf16x8*)(kr + (((4 + quad) ^ (l16 & 7)) * 8));

      short4v pB[2];
      for (int s = 0; s < 2; ++s) {
        f32x4 z = {0.f, 0.f, 0.f, 0.f};
        f32x4 st = __builtin_amdgcn_mfma_f32_16x16x32_bf16(kf0, qf[s][0], z, 0, 0, 0);
        st = __builtin_amdgcn_mfma_f32_16x16x32_bf16(kf1, qf[s][1], st, 0, 0, 0);
        union { bf16_t hh[4]; short4v s4; } u;
        for (int r = 0; r < 4; ++r) {
          float p = __builtin_amdgcn_exp2f(st[r]);   // Q pre-scaled by CEXP
          u.hh[r] = (bf16_t)p;
        }
        pB[s] = u.s4;
        lsum[s] = MFMA_PV(ones4, pB[s], lsum[s]);    // denominator on MFMA pipe
      }

      const int chunkbase = kb * 2 + (quad >> 1);
      const int coff = (quad & 1) * 4;
      for (int db = 0; db < 4; ++db) {
        short4v vf = *(const short4v*)&VtB[(db * 16 + l16) * 128 +
                                           ((chunkbase ^ l16) * 8) + coff];
        for (int s = 0; s < 2; ++s)
          accO[s][db] = MFMA_PV(vf, pB[s], accO[s][db]);
      }
    }
  }

  for (int s = 0; s < 2; ++s) {
    float inv = 1.f / lsum[s][0];          // all rows identical; no shuffles
    size_t tok = (size_t)b * SEQ + qw + s * 16 + l16;
    for (int db = 0; db < 4; ++db) {
      bf16_t o4[4];
      for (int r = 0; r < 4; ++r) o4[r] = (bf16_t)(accO[s][db][r] * inv);
      *(uint2*)&attn[tok * DMODEL + h * HD + db * 16 + quad * 4] = *(uint2*)o4;
    }
  }
}

// ------------------------------------------------------------- launch
extern "C" void kernel_launch(void* const* d_in, const int* in_sizes, int n_in,
                              void* d_out, int out_size, void* d_ws, size_t ws_size,
                              hipStream_t stream) {
  const void* x     = d_in[0];
  const void* w_qkv = d_in[1];
  const void* b_qkv = d_in[2];
  const void* w_out = d_in[3];
  const void* b_out = d_in[4];

  char* ws = (char*)d_ws;
  int*    flag  = (int*)ws;                                    // @0
  bf16_t* wqkvT = (bf16_t*)(ws + 4096);                        // 6.0 MB
  bf16_t* woutT = (bf16_t*)(ws + 6295552);                     // 2.0 MB
  float*  bqkvf = (float*)(ws + 8392704);
  float*  boutf = (float*)(ws + 8404992);
  bf16_t* qkv   = (bf16_t*)(ws + 8409088);                     // 8192x3072 bf16 (50.3 MB)
  bf16_t* xb    = (bf16_t*)(ws + 58740736);                    // 16.8 MB
  bf16_t* attn  = xb;                                          // alias (xb dead after gemm1)
  bf16_t* vTbuf = (bf16_t*)(ws + 75517952);                    // 16.8 MB -> end ~92.3 MB

  sniff_dtype<<<1, 256, 0, stream>>>((const uint4*)x, flag, b_qkv, b_out,
                                     bqkvf, boutf);

  conv_to_bf16<<<NOUT / 2048, 256, 0, stream>>>(x, xb, NOUT, flag);

  transpose_w2<<<dim3(128, 32), 256, 0, stream>>>(w_qkv, wqkvT, w_out, woutT, flag);

  gemm256_qkv<<<dim3(12, 32), 512, 0, stream>>>(
      xb, wqkvT, bqkvf, qkv, NTOK, 3072, 1024, vTbuf);

  attention_v12<<<dim3(BATCH * NH, SEQ / 256), 512, 0, stream>>>(qkv, vTbuf, attn);

  gemm_bt_bias<1><<<dim3(8, 64), 256, 0, stream>>>(
      attn, woutT, boutf, d_out, NTOK, 1024, 1024, flag);
}

// Round 8
// 291.131 us; speedup vs baseline: 1.0242x; 1.0242x over previous
//
#include <hip/hip_runtime.h>
#include <hip/hip_bf16.h>

// MHA forward. B=4, T=2048, D=1024, H=16, Hd=64. Inputs auto-detected f32/bf16.
// convert x + transpose weights (fused) -> QKV GEMM (256x256 4-phase, +bias;
// Q pre-scaled by log2e/8; V written transposed to vT in-epilogue) ->
// flash attention v13 (KVBLK=64, 32KB LDS, 4 blocks/CU) -> out GEMM.
// R4: never cap occupancy via __launch_bounds__ 2nd arg (spill disaster).
// R5: don't interleave P LDS writes into PV chain. R6: keep S live range to one kb.
// R7: all single-buffer variants stall ~120us on per-tile barrier drain.
// R8: v8 latency-bound at 2 waves/SIMD; v9 512-thr 32q/wave -> 4 waves/SIMD (101us).
// R9: v10 manual pipeline+stagger+setprio REGRESSED: manual ordering defeats
//     compiler sched (m141); intra-block stagger can't beat the shared barrier.
// R10: v11 no-LDS direct-global attention REGRESSED 3.5x: K-row stride 6KB ->
//     L1/TA issue serializes. LDS staging IS the coalescer. Keep LDS form.
// R12: lp-as-f32x4 REGRESSED: acc vectorization perturbed regalloc.
// R14: 256^2 4-phase gemm1 = parity with 128^2 (~90us): 384 blocks @ 1 block/CU
//     = 75% wave quantization; 2-buf LDS caps prefetch depth at 2-3 phases
//     (~500cy < HBM 900cy) - structurally stuck without more LDS. Accepted.
// R15: lsum-via-ones-MFMA WIN: attn 101->90.3, Mfma 43.7->56.9, VGPR 88->60.
// R16 (this round): VGPR=60 < 64 enables 8 waves/SIMD but 64KB LDS pinned us at
//     2 blocks/CU (Occ 35.7%). KVBLK 128->64: LDS 32KB -> 4 blocks/CU; extra
//     waves are INDEPENDENT blocks (no shared barrier) -> cross-block overlap
//     hides the QK/exp/PV burst lockstep. Also fuse conv+transpose (6->5 launches).

typedef __bf16 bf16_t;
typedef __bf16 bf16x8 __attribute__((ext_vector_type(8)));
typedef float f32x4 __attribute__((ext_vector_type(4)));
typedef short short4v __attribute__((ext_vector_type(4)));

#if __has_builtin(__builtin_amdgcn_mfma_f32_16x16x16_bf16)
typedef __bf16 bf16x4 __attribute__((ext_vector_type(4)));
#define MFMA_PV(va, vb, c) __builtin_amdgcn_mfma_f32_16x16x16_bf16( \
    __builtin_bit_cast(bf16x4, (va)), __builtin_bit_cast(bf16x4, (vb)), (c), 0, 0, 0)
#else
#define MFMA_PV(va, vb, c) __builtin_amdgcn_mfma_f32_16x16x16bf16_1k((va), (vb), (c), 0, 0, 0)
#endif

#define DMODEL 1024
#define NH     16
#define HD     64
#define BATCH  4
#define SEQ    2048
#define NTOK   (BATCH * SEQ)      // 8192
#define NOUT   (NTOK * DMODEL)    // 8388608
#define CEXP   0.1803368801111204f   // log2(e)/sqrt(64)

__device__ __forceinline__ void async_ld16(void* lds, const void* g) {
  __builtin_amdgcn_global_load_lds(
      (const __attribute__((address_space(1))) void*)g,
      (__attribute__((address_space(3))) void*)lds, 16, 0, 0);
}

// ------------------------------------------------------------- dtype sniff + biases
__global__ __launch_bounds__(256) void sniff_dtype(
    const uint4* __restrict__ x, int* __restrict__ flag,
    const void* __restrict__ sq, const void* __restrict__ so,
    float* __restrict__ dq, float* __restrict__ dofs) {
  int t = threadIdx.x;
  int nanish = 0, zc = 0;
  for (int j = 0; j < 4; ++j) {
    uint4 w = x[t + j * 256];
    unsigned u[4] = {w.x, w.y, w.z, w.w};
    for (int k = 0; k < 4; ++k) {
      unsigned lo = u[k] & 0xFFFFu, hi = u[k] >> 16;
      if ((lo & 0x7F80u) == 0x7F80u) nanish++;
      if ((hi & 0x7F80u) == 0x7F80u) nanish++;
      if (lo == 0) zc++;
      if (hi == 0) zc++;
    }
  }
  __shared__ int rn[256], rz[256];
  rn[t] = nanish; rz[t] = zc;
  __syncthreads();
  for (int s = 128; s > 0; s >>= 1) {
    if (t < s) { rn[t] += rn[t + s]; rz[t] += rz[t + s]; }
    __syncthreads();
  }
  const int f = (rn[0] > 4 || rz[0] > 2048) ? 1 : 0;   // 1 = f32 inputs
  if (t == 0) flag[0] = f;
  for (int j = 0; j < 16; ++j) {
    int i = j * 256 + t;                               // 0..4095
    if (i < 3072)
      dq[i] = f ? ((const float*)sq)[i] : (float)((const bf16_t*)sq)[i];
    else {
      int k = i - 3072;
      dofs[k] = f ? ((const float*)so)[k] : (float)((const bf16_t*)so)[k];
    }
  }
}

// ------------------------------------------------------------- conv + transpose (fused)
// blocks 0..4095: x -> xb (8 bf16/thread). blocks 4096..8191: weight transpose,
// flattened (128 col-tiles x 32 row-tiles); col-tile <96 = w_qkv, >=96 = w_out.
__global__ __launch_bounds__(256) void conv_and_transpose(
    const void* __restrict__ x, bf16_t* __restrict__ xb,
    const void* __restrict__ w0, bf16_t* __restrict__ out0,
    const void* __restrict__ w1, bf16_t* __restrict__ out1,
    const int* __restrict__ flag) {
  const int bb = blockIdx.x;
  if (bb < 4096) {
    int i = (bb * 256 + threadIdx.x) * 8;
    if (flag[0]) {
      const float4* s = (const float4*)((const float*)x + i);
      float4 a = s[0], b = s[1];
      bf16_t* o = xb + i;
      o[0] = (bf16_t)a.x; o[1] = (bf16_t)a.y; o[2] = (bf16_t)a.z; o[3] = (bf16_t)a.w;
      o[4] = (bf16_t)b.x; o[5] = (bf16_t)b.y; o[6] = (bf16_t)b.z; o[7] = (bf16_t)b.w;
    } else {
      *(uint4*)(xb + i) = *(const uint4*)((const bf16_t*)x + i);
    }
    return;
  }
  __shared__ bf16_t tile[32][33];
  const int idx = bb - 4096;
  const int bxT = idx & 127, byT = idx >> 7;
  const int tx = threadIdx.x & 31, ty = threadIdx.x >> 5;
  const bool second = bxT >= 96;
  const void* in = second ? w1 : w0;
  bf16_t* out = second ? out1 : out0;
  const int C = second ? 1024 : 3072;
  const int R = 1024;
  const int c0 = (second ? (bxT - 96) : bxT) * 32;
  const int r0 = byT * 32;
  if (flag[0]) {
    for (int i = 0; i < 4; ++i) {
      int r = ty + i * 8;
      tile[r][tx] = (bf16_t)((const float*)in)[(size_t)(r0 + r) * C + c0 + tx];
    }
  } else {
    for (int i = 0; i < 4; ++i) {
      int r = ty + i * 8;
      tile[r][tx] = ((const bf16_t*)in)[(size_t)(r0 + r) * C + c0 + tx];
    }
  }
  __syncthreads();
  for (int i = 0; i < 4; ++i) {
    int r = ty + i * 8;
    out[(size_t)(c0 + r) * R + r0 + tx] = tile[tx][r];
  }
}

// ------------------------------------------------------------- 128^2 GEMM (B^T) + bias
// MODE 1 only (out-proj): dyn f32/bf16 per flag. 2-phase dbuf, counted vmcnt.
template <int MODE>
__global__ __launch_bounds__(256) void gemm_bt_bias(
    const bf16_t* __restrict__ A, const bf16_t* __restrict__ Bt,
    const float* __restrict__ bias, void* __restrict__ Cout,
    int M, int N, int K, const int* __restrict__ flag) {
  __shared__ bf16_t sA[2][128 * 32];
  __shared__ bf16_t sB[2][128 * 32];
  const int t = threadIdx.x;
  const int wave = t >> 6, lane = t & 63;
  const int quad = lane >> 4, l16 = lane & 15;
  const int nwg = gridDim.x * gridDim.y;
  const int lin = blockIdx.y * gridDim.x + blockIdx.x;
  const int cpx = nwg >> 3;                    // nwg % 8 == 0 for our grids
  const int swz = (lin & 7) * cpx + (lin >> 3);
  const int bx = swz % gridDim.x, by = swz / gridDim.x;
  const int bM = by * 128, bN = bx * 128;
  const int m0w = (wave >> 1) * 64, n0w = (wave & 1) * 64;
  const int rowS = wave * 16 + (lane >> 2);
  const int kcS = (lane & 3) * 8;

  f32x4 acc[4][4] = {};

  auto stage = [&](int buf, int k0) {
    for (int r = 0; r < 2; ++r) {
      int row = r * 64 + rowS;
      async_ld16((char*)sA[buf] + r * 4096 + wave * 1024,
                 A + (size_t)(bM + row) * K + k0 + kcS);
      async_ld16((char*)sB[buf] + r * 4096 + wave * 1024,
                 Bt + (size_t)(bN + row) * K + k0 + kcS);
    }
  };

  const int nsteps = K >> 5;
  stage(0, 0);

  for (int s = 0; s < nsteps; ++s) {
    const int cur = s & 1;
    if (s + 1 < nsteps) {
      stage(cur ^ 1, (s + 1) << 5);
      asm volatile("s_waitcnt vmcnt(4)" ::: "memory");
    } else {
      asm volatile("s_waitcnt vmcnt(0)" ::: "memory");
    }
    __builtin_amdgcn_s_barrier();
    asm volatile("" ::: "memory");

    bf16x8 af[4], bfr[4];
    for (int i = 0; i < 4; ++i)
      af[i] = *(const bf16x8*)&sA[cur][(m0w + i * 16 + l16) * 32 + quad * 8];
    for (int j = 0; j < 4; ++j)
      bfr[j] = *(const bf16x8*)&sB[cur][(n0w + j * 16 + l16) * 32 + quad * 8];
    for (int i = 0; i < 4; ++i)
      for (int j = 0; j < 4; ++j)
        acc[i][j] = __builtin_amdgcn_mfma_f32_16x16x32_bf16(af[i], bfr[j], acc[i][j], 0, 0, 0);

    asm volatile("" ::: "memory");
    __builtin_amdgcn_s_barrier();
  }

  const bool f32out = (MODE == 1) && flag[0];
  for (int j = 0; j < 4; ++j) {
    int col = bN + n0w + j * 16 + l16;
    float bv = bias[col];
    for (int i = 0; i < 4; ++i) {
      int row0 = bM + m0w + i * 16 + quad * 4;
      for (int r = 0; r < 4; ++r) {
        float v = acc[i][j][r] + bv;
        if (f32out) ((float*)Cout)[(size_t)(row0 + r) * N + col] = v;
        else        ((bf16_t*)Cout)[(size_t)(row0 + r) * N + col] = (bf16_t)v;
      }
    }
  }
}

// ------------------------------------------------------------- 256^2 4-phase QKV GEMM
// (verified R6/R7; see R14 note — accepted at parity, byte-identical this round).
__global__ __launch_bounds__(512) void gemm256_qkv(
    const bf16_t* __restrict__ A, const bf16_t* __restrict__ Bt,
    const float* __restrict__ bias, bf16_t* __restrict__ Cout,
    int M, int N, int K, bf16_t* __restrict__ vT) {
  __shared__ __align__(16) char smem[131072];
  char* lds = smem;
  const int t = threadIdx.x;
  const int wave = t >> 6, lane = t & 63;
  const int quad = lane >> 4, l16 = lane & 15;
  const int wr = wave >> 2, wc = wave & 3;
  const int nwg = gridDim.x * gridDim.y;       // 384, %8==0
  const int lin = blockIdx.y * gridDim.x + blockIdx.x;
  const int cpx = nwg >> 3;
  const int swzb = (lin & 7) * cpx + (lin >> 3);
  const int bx = swzb % gridDim.x, by = swzb / gridDim.x;
  const int bM = by * 256, bN = bx * 256;

  const int srow = t >> 2;
  const int xr = ((srow >> 3) & 1) | (((srow >> 2) & 1) << 1);
  const int skl = ((t ^ xr) & 3) * 8;
  const size_t offA0 = (size_t)(bM + srow) * K + skl;
  const size_t offB0 = (size_t)(bN + srow) * K + skl;
  const size_t off1 = (size_t)128 * K;
  const int ldsw = wave * 1024;

#define STG_A(bufo, h, k0t) do {                                               \
    async_ld16(lds + (bufo) + (h) * 16384 + ldsw, A + offA0 + (k0t) + (h) * 32);\
    async_ld16(lds + (bufo) + (h) * 16384 + 8192 + ldsw,                       \
               A + offA0 + off1 + (k0t) + (h) * 32); } while (0)
#define STG_B(bufo, h, k0t) do {                                               \
    async_ld16(lds + (bufo) + 32768 + (h) * 16384 + ldsw,                      \
               Bt + offB0 + (k0t) + (h) * 32);                                 \
    async_ld16(lds + (bufo) + 32768 + (h) * 16384 + 8192 + ldsw,               \
               Bt + offB0 + off1 + (k0t) + (h) * 32); } while (0)

  int aoff[8], boff[4];
#pragma unroll
  for (int mf = 0; mf < 8; ++mf) {
    int r = wr * 128 + mf * 16 + l16;
    aoff[mf] = ((r << 6) + (quad << 4)) ^ (((r & 8) << 1) | ((r & 4) << 3));
  }
#pragma unroll
  for (int nf = 0; nf < 4; ++nf) {
    int r = wc * 64 + nf * 16 + l16;
    boff[nf] = 32768 + (((r << 6) + (quad << 4)) ^ (((r & 8) << 1) | ((r & 4) << 3)));
  }

  f32x4 acc[8][4] = {};
  bf16x8 af[4], bf[4];

#define LDA_SET(mfb, h, bufo) do {                                             \
    af[0] = *(const bf16x8*)(lds + (bufo) + (h) * 16384 + aoff[(mfb) + 0]);    \
    af[1] = *(const bf16x8*)(lds + (bufo) + (h) * 16384 + aoff[(mfb) + 1]);    \
    af[2] = *(const bf16x8*)(lds + (bufo) + (h) * 16384 + aoff[(mfb) + 2]);    \
    af[3] = *(const bf16x8*)(lds + (bufo) + (h) * 16384 + aoff[(mfb) + 3]); } while (0)
#define LDB_SET(h, bufo) do {                                                  \
    bf[0] = *(const bf16x8*)(lds + (bufo) + (h) * 16384 + boff[0]);            \
    bf[1] = *(const bf16x8*)(lds + (bufo) + (h) * 16384 + boff[1]);            \
    bf[2] = *(const bf16x8*)(lds + (bufo) + (h) * 16384 + boff[2]);            \
    bf[3] = *(const bf16x8*)(lds + (bufo) + (h) * 16384 + boff[3]); } while (0)
#define MFMA16(mfb) do {                                                       \
    _Pragma("unroll") for (int i_ = 0; i_ < 4; ++i_)                           \
      { _Pragma("unroll") for (int j_ = 0; j_ < 4; ++j_)                       \
        acc[(mfb) + i_][j_] = __builtin_amdgcn_mfma_f32_16x16x32_bf16(         \
            af[i_], bf[j_], acc[(mfb) + i_][j_], 0, 0, 0); } } while (0)
#define BAR1() do { __builtin_amdgcn_s_barrier(); asm volatile("" ::: "memory"); \
    __builtin_amdgcn_s_setprio(1); } while (0)
#define BAR2() do { __builtin_amdgcn_s_setprio(0);                             \
    asm volatile("" ::: "memory"); __builtin_amdgcn_s_barrier(); } while (0)

  const int NT = K >> 6;                       // 16
  STG_A(0, 0, 0); STG_B(0, 0, 0); STG_A(0, 1, 0); STG_B(0, 1, 0);
  STG_A(65536, 0, 64); STG_B(65536, 0, 64);
  asm volatile("s_waitcnt vmcnt(4)" ::: "memory");
  __builtin_amdgcn_s_barrier();
  asm volatile("" ::: "memory");

  for (int T = 0; T < NT; ++T) {
    const int bufo = (T & 1) << 16;
    const int obufo = bufo ^ 65536;
    const int k1 = (T + 1) << 6, k2 = (T + 2) << 6;
    LDA_SET(0, 0, bufo); LDB_SET(0, bufo);
    if (T + 1 < NT) STG_A(obufo, 1, k1);
    BAR1(); MFMA16(0); BAR2();
    LDA_SET(4, 0, bufo);
    if (T + 1 < NT) STG_B(obufo, 1, k1);
    BAR1(); MFMA16(4); BAR2();
    LDA_SET(0, 1, bufo); LDB_SET(1, bufo);
    if (T + 2 < NT) STG_A(bufo, 0, k2);
    BAR1(); MFMA16(0); BAR2();
    LDA_SET(4, 1, bufo);
    if (T + 2 < NT) {
      STG_B(bufo, 0, k2);
      asm volatile("s_waitcnt vmcnt(4)" ::: "memory");
    } else {
      asm volatile("s_waitcnt vmcnt(0)" ::: "memory");
    }
    BAR1(); MFMA16(4); BAR2();
  }

#pragma unroll
  for (int nf = 0; nf < 4; ++nf) {
    int col = bN + wc * 64 + nf * 16 + l16;
    float bv = bias[col];
#pragma unroll
    for (int mf = 0; mf < 8; ++mf) {
      int row0 = bM + wr * 128 + mf * 16 + quad * 4;
      if (col >= 2048) {
        int hh = (col - 2048) >> 6, dd = (col - 2048) & 63;
        bf16_t o4[4];
        for (int r = 0; r < 4; ++r) o4[r] = (bf16_t)(acc[mf][nf][r] + bv);
        size_t dst = ((((size_t)(row0 >> 11) * NH + hh) * HD + dd) << 11) | (row0 & 2047);
        *(uint2*)&vT[dst] = *(uint2*)o4;
      } else {
        float scale = (col < 1024) ? CEXP : 1.0f;
        for (int r = 0; r < 4; ++r)
          Cout[(size_t)(row0 + r) * N + col] = (bf16_t)((acc[mf][nf][r] + bv) * scale);
      }
    }
  }
#undef STG_A
#undef STG_B
#undef LDA_SET
#undef LDB_SET
#undef MFMA16
#undef BAR1
#undef BAR2
}

// ------------------------------------------------------------- flash attention v13
// v12 compute (lsum via ones-MFMA, verified 90.3us) with KVBLK 128->64:
// LDS 64KB->32KB -> 4 blocks/CU = 32 waves/CU (VGPR=60 <= 64 allows 8 w/SIMD).
// Extra waves are independent blocks (separate barriers) -> cross-block overlap
// hides the intra-block QK/exp/PV lockstep. Tiles: 32 x 64 keys; stage = 1 K +
// 1 V async per thread; kb loop 0..3. Same XOR swizzles (K by key&7 unchanged;
// V rows now 128B/8 chunks, swizzle by d&7).
__global__ __launch_bounds__(512) void attention_v13(
    const bf16_t* __restrict__ qkv, const bf16_t* __restrict__ vT,
    bf16_t* __restrict__ attn) {
  const int t = threadIdx.x;
  const int wave = t >> 6, lane = t & 63;           // wave 0..7
  const int quad = lane >> 4, l16 = lane & 15;
  const int bh = blockIdx.x, b = bh >> 4, h = bh & 15;
  const int qw = blockIdx.y * 256 + wave * 32;

  __shared__ bf16_t Kt[2][64 * 64];    // [key][d], 16B-chunk XOR swizzle by key&7
  __shared__ bf16_t Vt[2][64 * 64];    // [d][key], 16B-chunk XOR swizzle by d&7

  const bf16_t* qglob = qkv + (size_t)b * SEQ * 3072 + h * 64;
  const bf16_t* kglob = qglob + 1024;
  const bf16_t* vglob = vT + (size_t)bh * HD * SEQ;

  bf16x8 qf[2][2];
  for (int s = 0; s < 2; ++s) {
    const bf16_t* qrow = qglob + (size_t)(qw + s * 16 + l16) * 3072 + quad * 8;
    qf[s][0] = *(const bf16x8*)qrow;
    qf[s][1] = *(const bf16x8*)(qrow + 32);
  }

  f32x4 accO[2][4] = {};
  f32x4 lsum[2] = {};                       // denominator via ones-MFMA
  const short4v ones4 = {(short)0x3F80, (short)0x3F80, (short)0x3F80, (short)0x3F80};

  const int sRow = lane >> 3, sSlot = lane & 7;

  auto stageKV = [&](int buf, int kt) {
    int keyl = wave * 8 + sRow;               // wave stages keys [wave*8, +8)
    int gck = sSlot ^ (keyl & 7);
    async_ld16((char*)Kt[buf] + wave * 1024,
               kglob + (size_t)(kt + keyl) * 3072 + gck * 8);
    int d = wave * 8 + sRow;                  // wave stages V rows d [wave*8, +8)
    int gcv = sSlot ^ (d & 7);
    async_ld16((char*)Vt[buf] + wave * 1024,
               vglob + (size_t)d * SEQ + kt + gcv * 8);
  };

  stageKV(0, 0);

  for (int ti = 0; ti < SEQ / 64; ++ti) {
    const int buf = ti & 1;
    __syncthreads();                       // drain this tile's DMA + publish
    if (ti + 1 < SEQ / 64) stageKV(buf ^ 1, (ti + 1) * 64);

    const bf16_t* KtB = Kt[buf];
    const bf16_t* VtB = Vt[buf];

    for (int kb = 0; kb < 4; ++kb) {
      const bf16_t* kr = &KtB[(kb * 16 + l16) * 64];
      bf16x8 kf0 = *(const bf16x8*)(kr + ((quad ^ (l16 & 7)) * 8));
      bf16x8 kf1 = *(const bf16x8*)(kr + (((4 + quad) ^ (l16 & 7)) * 8));

      short4v pB[2];
      for (int s = 0; s < 2; ++s) {
        f32x4 z = {0.f, 0.f, 0.f, 0.f};
        f32x4 st = __builtin_amdgcn_mfma_f32_16x16x32_bf16(kf0, qf[s][0], z, 0, 0, 0);
        st = __builtin_amdgcn_mfma_f32_16x16x32_bf16(kf1, qf[s][1], st, 0, 0, 0);
        union { bf16_t hh[4]; short4v s4; } u;
        for (int r = 0; r < 4; ++r) {
          float p = __builtin_amdgcn_exp2f(st[r]);   // Q pre-scaled by CEXP
          u.hh[r] = (bf16_t)p;
        }
        pB[s] = u.s4;
        lsum[s] = MFMA_PV(ones4, pB[s], lsum[s]);    // denominator on MFMA pipe
      }

      const int chunkbase = kb * 2 + (quad >> 1);    // 0..7
      const int coff = (quad & 1) * 4;
      for (int db = 0; db < 4; ++db) {
        short4v vf = *(const short4v*)&VtB[(db * 16 + l16) * 64 +
                                           ((chunkbase ^ (l16 & 7)) * 8) + coff];
        for (int s = 0; s < 2; ++s)
          accO[s][db] = MFMA_PV(vf, pB[s], accO[s][db]);
      }
    }
  }

  for (int s = 0; s < 2; ++s) {
    float inv = 1.f / lsum[s][0];          // all rows identical; no shuffles
    size_t tok = (size_t)b * SEQ + qw + s * 16 + l16;
    for (int db = 0; db < 4; ++db) {
      bf16_t o4[4];
      for (int r = 0; r < 4; ++r) o4[r] = (bf16_t)(accO[s][db][r] * inv);
      *(uint2*)&attn[tok * DMODEL + h * HD + db * 16 + quad * 4] = *(uint2*)o4;
    }
  }
}

// ------------------------------------------------------------- launch
extern "C" void kernel_launch(void* const* d_in, const int* in_sizes, int n_in,
                              void* d_out, int out_size, void* d_ws, size_t ws_size,
                              hipStream_t stream) {
  const void* x     = d_in[0];
  const void* w_qkv = d_in[1];
  const void* b_qkv = d_in[2];
  const void* w_out = d_in[3];
  const void* b_out = d_in[4];

  char* ws = (char*)d_ws;
  int*    flag  = (int*)ws;                                    // @0
  bf16_t* wqkvT = (bf16_t*)(ws + 4096);                        // 6.0 MB
  bf16_t* woutT = (bf16_t*)(ws + 6295552);                     // 2.0 MB
  float*  bqkvf = (float*)(ws + 8392704);
  float*  boutf = (float*)(ws + 8404992);
  bf16_t* qkv   = (bf16_t*)(ws + 8409088);                     // 8192x3072 bf16 (50.3 MB)
  bf16_t* xb    = (bf16_t*)(ws + 58740736);                    // 16.8 MB
  bf16_t* attn  = xb;                                          // alias (xb dead after gemm1)
  bf16_t* vTbuf = (bf16_t*)(ws + 75517952);                    // 16.8 MB -> end ~92.3 MB

  sniff_dtype<<<1, 256, 0, stream>>>((const uint4*)x, flag, b_qkv, b_out,
                                     bqkvf, boutf);

  conv_and_transpose<<<8192, 256, 0, stream>>>(x, xb, w_qkv, wqkvT, w_out, woutT,
                                               flag);

  gemm256_qkv<<<dim3(12, 32), 512, 0, stream>>>(
      xb, wqkvT, bqkvf, qkv, NTOK, 3072, 1024, vTbuf);

  attention_v13<<<dim3(BATCH * NH, SEQ / 256), 512, 0, stream>>>(qkv, vTbuf, attn);

  gemm_bt_bias<1><<<dim3(8, 64), 256, 0, stream>>>(
      attn, woutT, boutf, d_out, NTOK, 1024, 1024, flag);
}

// Round 9
// 280.021 us; speedup vs baseline: 1.0649x; 1.0397x over previous
//
#include <hip/hip_runtime.h>
#include <hip/hip_bf16.h>

// MHA forward. B=4, T=2048, D=1024, H=16, Hd=64. Inputs auto-detected f32/bf16.
// convert x + transpose weights (fused) -> QKV GEMM (128x256/BK64 2-phase,
// zero wave-quantization; +bias; Q pre-scaled by log2e/8; V -> vT in-epilogue)
// -> flash attention v12 (KVBLK=128, lsum via ones-MFMA) -> out GEMM.
// R4: never cap occupancy via __launch_bounds__ 2nd arg (spill disaster).
// R5: don't interleave P LDS writes into PV chain. R6: keep S live range to one kb.
// R7: all single-buffer variants stall ~120us on per-tile barrier drain.
// R9: manual instr-order pinning defeats compiler sched (m141).
// R10: no-LDS attention REGRESSED 3.5x: K-row stride 6KB; LDS IS the coalescer.
// R12: lp-as-f32x4 REGRESSED: acc vectorization perturbed regalloc.
// R14: 256^2 4-phase gemm1 at 384 blocks = 1.5 rounds @ 1 block/CU -> 75%
//     quantization; pipeline depth capped by 128KB LDS. ~91.6us, Mfma 22%.
// R15: lsum-via-ones-MFMA WIN: attn 101->90.3, Mfma 43.7->56.9 (+VALU 39.5 ~ 96%
//     issue-saturated -> v12 is near this structure's ceiling). VGPR 88->60.
// R16: KVBLK=64 for 4 blocks/CU FAILED: grid has only 512 blocks -> still 2
//     resident; 2x barrier freq cost 5us. More blocks would 2x LDS-read BW
//     (23->46 TB/s, near 69 ceiling). Attention stays v12/KVBLK=128.
// R17 (this round): gemm1 -> 128x256/BK64: 768 blocks = EXACTLY 3 rounds @
//     1 block/CU (zero tail, was 75%). 96KB dbuf; 2 phases/tile x 16 MFMA;
//     uniform counted vmcnt(6) (3 groups x 3 loads in flight, issued 3 phases
//     ahead). Same swizzle + MODE2 epilogue, acc[4][4].

typedef __bf16 bf16_t;
typedef __bf16 bf16x8 __attribute__((ext_vector_type(8)));
typedef float f32x4 __attribute__((ext_vector_type(4)));
typedef short short4v __attribute__((ext_vector_type(4)));

#if __has_builtin(__builtin_amdgcn_mfma_f32_16x16x16_bf16)
typedef __bf16 bf16x4 __attribute__((ext_vector_type(4)));
#define MFMA_PV(va, vb, c) __builtin_amdgcn_mfma_f32_16x16x16_bf16( \
    __builtin_bit_cast(bf16x4, (va)), __builtin_bit_cast(bf16x4, (vb)), (c), 0, 0, 0)
#else
#define MFMA_PV(va, vb, c) __builtin_amdgcn_mfma_f32_16x16x16bf16_1k((va), (vb), (c), 0, 0, 0)
#endif

#define DMODEL 1024
#define NH     16
#define HD     64
#define BATCH  4
#define SEQ    2048
#define NTOK   (BATCH * SEQ)      // 8192
#define NOUT   (NTOK * DMODEL)    // 8388608
#define CEXP   0.1803368801111204f   // log2(e)/sqrt(64)

__device__ __forceinline__ void async_ld16(void* lds, const void* g) {
  __builtin_amdgcn_global_load_lds(
      (const __attribute__((address_space(1))) void*)g,
      (__attribute__((address_space(3))) void*)lds, 16, 0, 0);
}

// ------------------------------------------------------------- dtype sniff + biases
__global__ __launch_bounds__(256) void sniff_dtype(
    const uint4* __restrict__ x, int* __restrict__ flag,
    const void* __restrict__ sq, const void* __restrict__ so,
    float* __restrict__ dq, float* __restrict__ dofs) {
  int t = threadIdx.x;
  int nanish = 0, zc = 0;
  for (int j = 0; j < 4; ++j) {
    uint4 w = x[t + j * 256];
    unsigned u[4] = {w.x, w.y, w.z, w.w};
    for (int k = 0; k < 4; ++k) {
      unsigned lo = u[k] & 0xFFFFu, hi = u[k] >> 16;
      if ((lo & 0x7F80u) == 0x7F80u) nanish++;
      if ((hi & 0x7F80u) == 0x7F80u) nanish++;
      if (lo == 0) zc++;
      if (hi == 0) zc++;
    }
  }
  __shared__ int rn[256], rz[256];
  rn[t] = nanish; rz[t] = zc;
  __syncthreads();
  for (int s = 128; s > 0; s >>= 1) {
    if (t < s) { rn[t] += rn[t + s]; rz[t] += rz[t + s]; }
    __syncthreads();
  }
  const int f = (rn[0] > 4 || rz[0] > 2048) ? 1 : 0;   // 1 = f32 inputs
  if (t == 0) flag[0] = f;
  for (int j = 0; j < 16; ++j) {
    int i = j * 256 + t;                               // 0..4095
    if (i < 3072)
      dq[i] = f ? ((const float*)sq)[i] : (float)((const bf16_t*)sq)[i];
    else {
      int k = i - 3072;
      dofs[k] = f ? ((const float*)so)[k] : (float)((const bf16_t*)so)[k];
    }
  }
}

// ------------------------------------------------------------- conv + transpose (fused)
// blocks 0..4095: x -> xb (8 bf16/thread). blocks 4096..8191: weight transpose,
// flattened (128 col-tiles x 32 row-tiles); col-tile <96 = w_qkv, >=96 = w_out.
__global__ __launch_bounds__(256) void conv_and_transpose(
    const void* __restrict__ x, bf16_t* __restrict__ xb,
    const void* __restrict__ w0, bf16_t* __restrict__ out0,
    const void* __restrict__ w1, bf16_t* __restrict__ out1,
    const int* __restrict__ flag) {
  const int bb = blockIdx.x;
  if (bb < 4096) {
    int i = (bb * 256 + threadIdx.x) * 8;
    if (flag[0]) {
      const float4* s = (const float4*)((const float*)x + i);
      float4 a = s[0], b = s[1];
      bf16_t* o = xb + i;
      o[0] = (bf16_t)a.x; o[1] = (bf16_t)a.y; o[2] = (bf16_t)a.z; o[3] = (bf16_t)a.w;
      o[4] = (bf16_t)b.x; o[5] = (bf16_t)b.y; o[6] = (bf16_t)b.z; o[7] = (bf16_t)b.w;
    } else {
      *(uint4*)(xb + i) = *(const uint4*)((const bf16_t*)x + i);
    }
    return;
  }
  __shared__ bf16_t tile[32][33];
  const int idx = bb - 4096;
  const int bxT = idx & 127, byT = idx >> 7;
  const int tx = threadIdx.x & 31, ty = threadIdx.x >> 5;
  const bool second = bxT >= 96;
  const void* in = second ? w1 : w0;
  bf16_t* out = second ? out1 : out0;
  const int C = second ? 1024 : 3072;
  const int R = 1024;
  const int c0 = (second ? (bxT - 96) : bxT) * 32;
  const int r0 = byT * 32;
  if (flag[0]) {
    for (int i = 0; i < 4; ++i) {
      int r = ty + i * 8;
      tile[r][tx] = (bf16_t)((const float*)in)[(size_t)(r0 + r) * C + c0 + tx];
    }
  } else {
    for (int i = 0; i < 4; ++i) {
      int r = ty + i * 8;
      tile[r][tx] = ((const bf16_t*)in)[(size_t)(r0 + r) * C + c0 + tx];
    }
  }
  __syncthreads();
  for (int i = 0; i < 4; ++i) {
    int r = ty + i * 8;
    out[(size_t)(c0 + r) * R + r0 + tx] = tile[tx][r];
  }
}

// ------------------------------------------------------------- 128^2 GEMM (B^T) + bias
// MODE 1 only (out-proj): dyn f32/bf16 per flag. 2-phase dbuf, counted vmcnt.
template <int MODE>
__global__ __launch_bounds__(256) void gemm_bt_bias(
    const bf16_t* __restrict__ A, const bf16_t* __restrict__ Bt,
    const float* __restrict__ bias, void* __restrict__ Cout,
    int M, int N, int K, const int* __restrict__ flag) {
  __shared__ bf16_t sA[2][128 * 32];
  __shared__ bf16_t sB[2][128 * 32];
  const int t = threadIdx.x;
  const int wave = t >> 6, lane = t & 63;
  const int quad = lane >> 4, l16 = lane & 15;
  const int nwg = gridDim.x * gridDim.y;
  const int lin = blockIdx.y * gridDim.x + blockIdx.x;
  const int cpx = nwg >> 3;                    // nwg % 8 == 0 for our grids
  const int swz = (lin & 7) * cpx + (lin >> 3);
  const int bx = swz % gridDim.x, by = swz / gridDim.x;
  const int bM = by * 128, bN = bx * 128;
  const int m0w = (wave >> 1) * 64, n0w = (wave & 1) * 64;
  const int rowS = wave * 16 + (lane >> 2);
  const int kcS = (lane & 3) * 8;

  f32x4 acc[4][4] = {};

  auto stage = [&](int buf, int k0) {
    for (int r = 0; r < 2; ++r) {
      int row = r * 64 + rowS;
      async_ld16((char*)sA[buf] + r * 4096 + wave * 1024,
                 A + (size_t)(bM + row) * K + k0 + kcS);
      async_ld16((char*)sB[buf] + r * 4096 + wave * 1024,
                 Bt + (size_t)(bN + row) * K + k0 + kcS);
    }
  };

  const int nsteps = K >> 5;
  stage(0, 0);

  for (int s = 0; s < nsteps; ++s) {
    const int cur = s & 1;
    if (s + 1 < nsteps) {
      stage(cur ^ 1, (s + 1) << 5);
      asm volatile("s_waitcnt vmcnt(4)" ::: "memory");
    } else {
      asm volatile("s_waitcnt vmcnt(0)" ::: "memory");
    }
    __builtin_amdgcn_s_barrier();
    asm volatile("" ::: "memory");

    bf16x8 af[4], bfr[4];
    for (int i = 0; i < 4; ++i)
      af[i] = *(const bf16x8*)&sA[cur][(m0w + i * 16 + l16) * 32 + quad * 8];
    for (int j = 0; j < 4; ++j)
      bfr[j] = *(const bf16x8*)&sB[cur][(n0w + j * 16 + l16) * 32 + quad * 8];
    for (int i = 0; i < 4; ++i)
      for (int j = 0; j < 4; ++j)
        acc[i][j] = __builtin_amdgcn_mfma_f32_16x16x32_bf16(af[i], bfr[j], acc[i][j], 0, 0, 0);

    asm volatile("" ::: "memory");
    __builtin_amdgcn_s_barrier();
  }

  const bool f32out = (MODE == 1) && flag[0];
  for (int j = 0; j < 4; ++j) {
    int col = bN + n0w + j * 16 + l16;
    float bv = bias[col];
    for (int i = 0; i < 4; ++i) {
      int row0 = bM + m0w + i * 16 + quad * 4;
      for (int r = 0; r < 4; ++r) {
        float v = acc[i][j][r] + bv;
        if (f32out) ((float*)Cout)[(size_t)(row0 + r) * N + col] = v;
        else        ((bf16_t*)Cout)[(size_t)(row0 + r) * N + col] = (bf16_t)v;
      }
    }
  }
}

// ------------------------------------------------------------- 128x256 QKV GEMM
// Zero-quantization retile of the QKV GEMM (R17): grid 12x64 = 768 blocks =
// exactly 3 rounds @ 1 block/CU. 512 thr = 8 waves (2M x 4N); per-wave 64x64 =
// acc[4][4]. K-tile BK=64 = 2 halves; per half: A unit [128][32] (8KB) + B unit
// [256][32] (16KB). 2-tile dbuf = 96KB. Groups (A+B halves, 3 loads/thread)
// issued 3 phases ahead; uniform counted vmcnt(6)/phase. XOR swizzle
// byte ^= ((row&8)<<1)|((row&4)<<3) on reads; gload_lds dest linear, source
// k-chunk pre-inverse-swizzled. MODE2 epilogue: Q cols x CEXP, V cols -> vT.
__global__ __launch_bounds__(512) void gemm_qkv_v2(
    const bf16_t* __restrict__ A, const bf16_t* __restrict__ Bt,
    const float* __restrict__ bias, bf16_t* __restrict__ Cout,
    int M, int N, int K, bf16_t* __restrict__ vT) {
  __shared__ __align__(16) char smem[98304];
  char* lds = smem;
  const int t = threadIdx.x;
  const int wave = t >> 6, lane = t & 63;
  const int quad = lane >> 4, l16 = lane & 15;
  const int wr = wave >> 2, wc = wave & 3;     // 2M x 4N
  const int nwg = gridDim.x * gridDim.y;       // 768, %8==0
  const int lin = blockIdx.y * gridDim.x + blockIdx.x;
  const int cpx = nwg >> 3;
  const int swzb = (lin & 7) * cpx + (lin >> 3);
  const int bx = swzb % gridDim.x, by = swzb / gridDim.x;
  const int bM = by * 128, bN = bx * 256;

  // staging: thread t covers LDS row t>>2 (A: 0..127; B: t>>2 and 128+(t>>2)),
  // chunk t&3. Source k-chunk pre-inverse-swizzled so linear dest + swizzled
  // read agree (same involution).
  const int srow = t >> 2;
  const int xr = ((srow >> 3) & 1) | (((srow >> 2) & 1) << 1);
  const int skl = ((t ^ xr) & 3) * 8;
  const size_t offA = (size_t)(bM + srow) * K + skl;
  const size_t offB = (size_t)(bN + srow) * K + skl;
  const size_t offB2 = offB + (size_t)128 * K;

  // group g: tile=g>>1, half=g&1, buf=(g>>1)&1. 3 async loads.
#define STG(g) do {                                                            \
    const int tile_ = (g) >> 1, half_ = (g) & 1;                               \
    const int kk_ = tile_ * 64 + half_ * 32;                                   \
    char* base_ = lds + ((tile_ & 1) ? 49152 : 0);                             \
    async_ld16(base_ + half_ * 8192 + t * 16, A + offA + kk_);                 \
    async_ld16(base_ + 16384 + half_ * 16384 + t * 16, Bt + offB + kk_);       \
    async_ld16(base_ + 16384 + half_ * 16384 + 8192 + t * 16,                  \
               Bt + offB2 + kk_); } while (0)

  int aoff[4], boff[4];
#pragma unroll
  for (int mf = 0; mf < 4; ++mf) {
    int r = wr * 64 + mf * 16 + l16;           // 0..127
    aoff[mf] = ((r << 6) + (quad << 4)) ^ (((r & 8) << 1) | ((r & 4) << 3));
  }
#pragma unroll
  for (int nf = 0; nf < 4; ++nf) {
    int r = wc * 64 + nf * 16 + l16;           // 0..255
    boff[nf] = ((r << 6) + (quad << 4)) ^ (((r & 8) << 1) | ((r & 4) << 3));
  }

  f32x4 acc[4][4] = {};
  const int NT = K >> 6;                       // 16 tiles, 32 groups

  STG(0); STG(1); STG(2);
  asm volatile("s_waitcnt vmcnt(6)" ::: "memory");
  __builtin_amdgcn_s_barrier();
  asm volatile("" ::: "memory");

#define PHASE(T, h) do {                                                       \
    const int bufo_ = ((T) & 1) * 49152;                                       \
    bf16x8 af[4], bf[4];                                                       \
    _Pragma("unroll") for (int i_ = 0; i_ < 4; ++i_)                           \
      af[i_] = *(const bf16x8*)(lds + bufo_ + (h) * 8192 + aoff[i_]);          \
    _Pragma("unroll") for (int j_ = 0; j_ < 4; ++j_)                           \
      bf[j_] = *(const bf16x8*)(lds + bufo_ + 16384 + (h) * 16384 + boff[j_]); \
    const int n_ = 2 * (T) + (h);                                              \
    if (n_ + 3 < 2 * NT) {                                                     \
      STG(n_ + 3);                                                             \
      asm volatile("s_waitcnt vmcnt(6)" ::: "memory");                         \
    } else if (n_ == 2 * NT - 3) {                                             \
      asm volatile("s_waitcnt vmcnt(3)" ::: "memory");                         \
    } else if (n_ == 2 * NT - 2) {                                             \
      asm volatile("s_waitcnt vmcnt(0)" ::: "memory");                         \
    }                                                                          \
    __builtin_amdgcn_s_barrier();                                              \
    asm volatile("" ::: "memory");                                             \
    __builtin_amdgcn_s_setprio(1);                                             \
    _Pragma("unroll") for (int i_ = 0; i_ < 4; ++i_)                           \
      { _Pragma("unroll") for (int j_ = 0; j_ < 4; ++j_)                       \
        acc[i_][j_] = __builtin_amdgcn_mfma_f32_16x16x32_bf16(                 \
            af[i_], bf[j_], acc[i_][j_], 0, 0, 0); }                           \
    __builtin_amdgcn_s_setprio(0);                                             \
    asm volatile("" ::: "memory");                                             \
    __builtin_amdgcn_s_barrier(); } while (0)

  for (int T = 0; T < NT; ++T) {
    PHASE(T, 0);
    PHASE(T, 1);
  }

  // MODE2 epilogue: bias; Q cols (<1024) x CEXP; V cols (>=2048) -> vT scatter.
#pragma unroll
  for (int nf = 0; nf < 4; ++nf) {
    int col = bN + wc * 64 + nf * 16 + l16;
    float bv = bias[col];
#pragma unroll
    for (int mf = 0; mf < 4; ++mf) {
      int row0 = bM + wr * 64 + mf * 16 + quad * 4;
      if (col >= 2048) {
        int hh = (col - 2048) >> 6, dd = (col - 2048) & 63;
        bf16_t o4[4];
        for (int r = 0; r < 4; ++r) o4[r] = (bf16_t)(acc[mf][nf][r] + bv);
        size_t dst = ((((size_t)(row0 >> 11) * NH + hh) * HD + dd) << 11) | (row0 & 2047);
        *(uint2*)&vT[dst] = *(uint2*)o4;
      } else {
        float scale = (col < 1024) ? CEXP : 1.0f;
        for (int r = 0; r < 4; ++r)
          Cout[(size_t)(row0 + r) * N + col] = (bf16_t)((acc[mf][nf][r] + bv) * scale);
      }
    }
  }
#undef STG
#undef PHASE
}

// ------------------------------------------------------------- flash attention v12
// (verified 90.3us R7; restored after R16's KVBLK=64 regression.)
// Grid (64, 8) x 512 thr; KVBLK=128; 64KB LDS dbuf; wave owns 32 q (2 subtiles).
// S^T via 16x16x32 (Q pre-scaled by CEXP); exp2 direct; PV via 16x16x16 from
// regs; softmax denominator on the MFMA pipe: lsum = MFMA(ones, P, lsum),
// epilogue reads lsum[0] (no shuffles). Mfma 57 + VALU 39 ~ 96% issue-saturated.
__global__ __launch_bounds__(512) void attention_v12(
    const bf16_t* __restrict__ qkv, const bf16_t* __restrict__ vT,
    bf16_t* __restrict__ attn) {
  const int t = threadIdx.x;
  const int wave = t >> 6, lane = t & 63;           // wave 0..7
  const int quad = lane >> 4, l16 = lane & 15;
  const int bh = blockIdx.x, b = bh >> 4, h = bh & 15;
  const int qw = blockIdx.y * 256 + wave * 32;

  __shared__ bf16_t Kt[2][128 * 64];   // [key][d], 16B-chunk XOR swizzle by key&7
  __shared__ bf16_t Vt[2][64 * 128];   // [d][key], 16B-chunk XOR swizzle by d&15

  const bf16_t* qglob = qkv + (size_t)b * SEQ * 3072 + h * 64;
  const bf16_t* kglob = qglob + 1024;
  const bf16_t* vglob = vT + (size_t)bh * HD * SEQ;

  bf16x8 qf[2][2];
  for (int s = 0; s < 2; ++s) {
    const bf16_t* qrow = qglob + (size_t)(qw + s * 16 + l16) * 3072 + quad * 8;
    qf[s][0] = *(const bf16x8*)qrow;
    qf[s][1] = *(const bf16x8*)(qrow + 32);
  }

  f32x4 accO[2][4] = {};
  f32x4 lsum[2] = {};                       // denominator via ones-MFMA
  const short4v ones4 = {(short)0x3F80, (short)0x3F80, (short)0x3F80, (short)0x3F80};

  const int kRow = lane >> 3, kSlot = lane & 7;
  const int vRow = lane >> 4, vSlot = lane & 15;

  auto stageKV = [&](int buf, int kt) {
    for (int j = 0; j < 2; ++j) {   // K: wave stages keys [wave*16, +16)
      int keyl = wave * 16 + j * 8 + kRow;
      int gc = kSlot ^ (keyl & 7);
      async_ld16((char*)Kt[buf] + (wave * 16 + j * 8) * 128,
                 kglob + (size_t)(kt + keyl) * 3072 + gc * 8);
    }
    for (int j = 0; j < 2; ++j) {   // V: wave stages d [wave*8, +8)
      int d = wave * 8 + j * 4 + vRow;
      int gc = vSlot ^ (d & 15);
      async_ld16((char*)Vt[buf] + (wave * 8 + j * 4) * 256,
                 vglob + (size_t)d * SEQ + kt + gc * 8);
    }
  };

  stageKV(0, 0);

  for (int ti = 0; ti < SEQ / 128; ++ti) {
    const int buf = ti & 1;
    __syncthreads();                       // drain this tile's DMA + publish
    if (ti + 1 < SEQ / 128) stageKV(buf ^ 1, (ti + 1) * 128);

    const bf16_t* KtB = Kt[buf];
    const bf16_t* VtB = Vt[buf];

    for (int kb = 0; kb < 8; ++kb) {
      const bf16_t* kr = &KtB[(kb * 16 + l16) * 64];
      bf16x8 kf0 = *(const bf16x8*)(kr + ((quad ^ (l16 & 7)) * 8));
      bf16x8 kf1 = *(const bf16x8*)(kr + (((4 + quad) ^ (l16 & 7)) * 8));

      short4v pB[2];
      for (int s = 0; s < 2; ++s) {
        f32x4 z = {0.f, 0.f, 0.f, 0.f};
        f32x4 st = __builtin_amdgcn_mfma_f32_16x16x32_bf16(kf0, qf[s][0], z, 0, 0, 0);
        st = __builtin_amdgcn_mfma_f32_16x16x32_bf16(kf1, qf[s][1], st, 0, 0, 0);
        union { bf16_t hh[4]; short4v s4; } u;
        for (int r = 0; r < 4; ++r) {
          float p = __builtin_amdgcn_exp2f(st[r]);   // Q pre-scaled by CEXP
          u.hh[r] = (bf16_t)p;
        }
        pB[s] = u.s4;
        lsum[s] = MFMA_PV(ones4, pB[s], lsum[s]);    // denominator on MFMA pipe
      }

      const int chunkbase = kb * 2 + (quad >> 1);
      const int coff = (quad & 1) * 4;
      for (int db = 0; db < 4; ++db) {
        short4v vf = *(const short4v*)&VtB[(db * 16 + l16) * 128 +
                                           ((chunkbase ^ l16) * 8) + coff];
        for (int s = 0; s < 2; ++s)
          accO[s][db] = MFMA_PV(vf, pB[s], accO[s][db]);
      }
    }
  }

  for (int s = 0; s < 2; ++s) {
    float inv = 1.f / lsum[s][0];          // all rows identical; no shuffles
    size_t tok = (size_t)b * SEQ + qw + s * 16 + l16;
    for (int db = 0; db < 4; ++db) {
      bf16_t o4[4];
      for (int r = 0; r < 4; ++r) o4[r] = (bf16_t)(accO[s][db][r] * inv);
      *(uint2*)&attn[tok * DMODEL + h * HD + db * 16 + quad * 4] = *(uint2*)o4;
    }
  }
}

// ------------------------------------------------------------- launch
extern "C" void kernel_launch(void* const* d_in, const int* in_sizes, int n_in,
                              void* d_out, int out_size, void* d_ws, size_t ws_size,
                              hipStream_t stream) {
  const void* x     = d_in[0];
  const void* w_qkv = d_in[1];
  const void* b_qkv = d_in[2];
  const void* w_out = d_in[3];
  const void* b_out = d_in[4];

  char* ws = (char*)d_ws;
  int*    flag  = (int*)ws;                                    // @0
  bf16_t* wqkvT = (bf16_t*)(ws + 4096);                        // 6.0 MB
  bf16_t* woutT = (bf16_t*)(ws + 6295552);                     // 2.0 MB
  float*  bqkvf = (float*)(ws + 8392704);
  float*  boutf = (float*)(ws + 8404992);
  bf16_t* qkv   = (bf16_t*)(ws + 8409088);                     // 8192x3072 bf16 (50.3 MB)
  bf16_t* xb    = (bf16_t*)(ws + 58740736);                    // 16.8 MB
  bf16_t* attn  = xb;                                          // alias (xb dead after gemm1)
  bf16_t* vTbuf = (bf16_t*)(ws + 75517952);                    // 16.8 MB -> end ~92.3 MB

  sniff_dtype<<<1, 256, 0, stream>>>((const uint4*)x, flag, b_qkv, b_out,
                                     bqkvf, boutf);

  conv_and_transpose<<<8192, 256, 0, stream>>>(x, xb, w_qkv, wqkvT, w_out, woutT,
                                               flag);

  gemm_qkv_v2<<<dim3(12, 64), 512, 0, stream>>>(
      xb, wqkvT, bqkvf, qkv, NTOK, 3072, 1024, vTbuf);

  attention_v12<<<dim3(BATCH * NH, SEQ / 256), 512, 0, stream>>>(qkv, vTbuf, attn);

  gemm_bt_bias<1><<<dim3(8, 64), 256, 0, stream>>>(
      attn, woutT, boutf, d_out, NTOK, 1024, 1024, flag);
}

// Round 10
// 278.259 us; speedup vs baseline: 1.0716x; 1.0063x over previous
//
#include <hip/hip_runtime.h>
#include <hip/hip_bf16.h>

// MHA forward. B=4, T=2048, D=1024, H=16, Hd=64. Inputs auto-detected f32/bf16.
// convert x + transpose weights (fused) -> QKV GEMM (128x256/BK64 2-phase,
// zero wave-quantization; +bias; Q pre-scaled by log2e/8; V -> vT in-epilogue)
// -> flash attention v12 (KVBLK=128, lsum via ones-MFMA) -> out GEMM
// (same 128x256 structure, 256 blocks = 1 round, dyn f32/bf16 out).
// R4: never cap occupancy via __launch_bounds__ 2nd arg (spill disaster).
// R5: don't interleave P LDS writes into PV chain. R6: keep S live range to one kb.
// R7: all single-buffer variants stall ~120us on per-tile barrier drain.
// R9: manual instr-order pinning defeats compiler sched (m141).
// R10: no-LDS attention REGRESSED 3.5x: K-row stride 6KB; LDS IS the coalescer.
// R12: lp-as-f32x4 REGRESSED: acc vectorization perturbed regalloc.
// R14: 256^2 4-phase gemm1 at 384 blocks = 75% wave quantization (~91.6us).
// R15: lsum-via-ones-MFMA WIN: attn 101->90.3, Mfma 43.7->56.9 (+VALU ~ 96%
//     issue-saturated -> v12 near this structure's ceiling). VGPR 88->60.
//     PV-as-K=32 considered: needs cross-quad permlane repack of P, cost ~ gain.
// R16: KVBLK=64 for 4 blocks/CU FAILED: grid only 512 blocks -> still 2
//     resident; 2x barrier freq cost 5us. Attention stays KVBLK=128.
// R17: gemm1 128x256/BK64, 768 blocks = 3 exact rounds: 91.6 -> ~74us (WIN,
//     quantization was binding). 96KB dbuf, vmcnt(6), 2 phases/tile.
// R18 (this round): gemm2 -> same v2 structure via template<MODE>: 4x64 grid =
//     256 blocks = EXACTLY 1 round (old 128^2 ran 2 rounds of 2-barrier loop).
//     Projected 31 -> ~25us (74/3 per round). Old 128^2 kernel retired.

typedef __bf16 bf16_t;
typedef __bf16 bf16x8 __attribute__((ext_vector_type(8)));
typedef float f32x4 __attribute__((ext_vector_type(4)));
typedef short short4v __attribute__((ext_vector_type(4)));

#if __has_builtin(__builtin_amdgcn_mfma_f32_16x16x16_bf16)
typedef __bf16 bf16x4 __attribute__((ext_vector_type(4)));
#define MFMA_PV(va, vb, c) __builtin_amdgcn_mfma_f32_16x16x16_bf16( \
    __builtin_bit_cast(bf16x4, (va)), __builtin_bit_cast(bf16x4, (vb)), (c), 0, 0, 0)
#else
#define MFMA_PV(va, vb, c) __builtin_amdgcn_mfma_f32_16x16x16bf16_1k((va), (vb), (c), 0, 0, 0)
#endif

#define DMODEL 1024
#define NH     16
#define HD     64
#define BATCH  4
#define SEQ    2048
#define NTOK   (BATCH * SEQ)      // 8192
#define NOUT   (NTOK * DMODEL)    // 8388608
#define CEXP   0.1803368801111204f   // log2(e)/sqrt(64)

__device__ __forceinline__ void async_ld16(void* lds, const void* g) {
  __builtin_amdgcn_global_load_lds(
      (const __attribute__((address_space(1))) void*)g,
      (__attribute__((address_space(3))) void*)lds, 16, 0, 0);
}

// ------------------------------------------------------------- dtype sniff + biases
__global__ __launch_bounds__(256) void sniff_dtype(
    const uint4* __restrict__ x, int* __restrict__ flag,
    const void* __restrict__ sq, const void* __restrict__ so,
    float* __restrict__ dq, float* __restrict__ dofs) {
  int t = threadIdx.x;
  int nanish = 0, zc = 0;
  for (int j = 0; j < 4; ++j) {
    uint4 w = x[t + j * 256];
    unsigned u[4] = {w.x, w.y, w.z, w.w};
    for (int k = 0; k < 4; ++k) {
      unsigned lo = u[k] & 0xFFFFu, hi = u[k] >> 16;
      if ((lo & 0x7F80u) == 0x7F80u) nanish++;
      if ((hi & 0x7F80u) == 0x7F80u) nanish++;
      if (lo == 0) zc++;
      if (hi == 0) zc++;
    }
  }
  __shared__ int rn[256], rz[256];
  rn[t] = nanish; rz[t] = zc;
  __syncthreads();
  for (int s = 128; s > 0; s >>= 1) {
    if (t < s) { rn[t] += rn[t + s]; rz[t] += rz[t + s]; }
    __syncthreads();
  }
  const int f = (rn[0] > 4 || rz[0] > 2048) ? 1 : 0;   // 1 = f32 inputs
  if (t == 0) flag[0] = f;
  for (int j = 0; j < 16; ++j) {
    int i = j * 256 + t;                               // 0..4095
    if (i < 3072)
      dq[i] = f ? ((const float*)sq)[i] : (float)((const bf16_t*)sq)[i];
    else {
      int k = i - 3072;
      dofs[k] = f ? ((const float*)so)[k] : (float)((const bf16_t*)so)[k];
    }
  }
}

// ------------------------------------------------------------- conv + transpose (fused)
// blocks 0..4095: x -> xb (8 bf16/thread). blocks 4096..8191: weight transpose,
// flattened (128 col-tiles x 32 row-tiles); col-tile <96 = w_qkv, >=96 = w_out.
__global__ __launch_bounds__(256) void conv_and_transpose(
    const void* __restrict__ x, bf16_t* __restrict__ xb,
    const void* __restrict__ w0, bf16_t* __restrict__ out0,
    const void* __restrict__ w1, bf16_t* __restrict__ out1,
    const int* __restrict__ flag) {
  const int bb = blockIdx.x;
  if (bb < 4096) {
    int i = (bb * 256 + threadIdx.x) * 8;
    if (flag[0]) {
      const float4* s = (const float4*)((const float*)x + i);
      float4 a = s[0], b = s[1];
      bf16_t* o = xb + i;
      o[0] = (bf16_t)a.x; o[1] = (bf16_t)a.y; o[2] = (bf16_t)a.z; o[3] = (bf16_t)a.w;
      o[4] = (bf16_t)b.x; o[5] = (bf16_t)b.y; o[6] = (bf16_t)b.z; o[7] = (bf16_t)b.w;
    } else {
      *(uint4*)(xb + i) = *(const uint4*)((const bf16_t*)x + i);
    }
    return;
  }
  __shared__ bf16_t tile[32][33];
  const int idx = bb - 4096;
  const int bxT = idx & 127, byT = idx >> 7;
  const int tx = threadIdx.x & 31, ty = threadIdx.x >> 5;
  const bool second = bxT >= 96;
  const void* in = second ? w1 : w0;
  bf16_t* out = second ? out1 : out0;
  const int C = second ? 1024 : 3072;
  const int R = 1024;
  const int c0 = (second ? (bxT - 96) : bxT) * 32;
  const int r0 = byT * 32;
  if (flag[0]) {
    for (int i = 0; i < 4; ++i) {
      int r = ty + i * 8;
      tile[r][tx] = (bf16_t)((const float*)in)[(size_t)(r0 + r) * C + c0 + tx];
    }
  } else {
    for (int i = 0; i < 4; ++i) {
      int r = ty + i * 8;
      tile[r][tx] = ((const bf16_t*)in)[(size_t)(r0 + r) * C + c0 + tx];
    }
  }
  __syncthreads();
  for (int i = 0; i < 4; ++i) {
    int r = ty + i * 8;
    out[(size_t)(c0 + r) * R + r0 + tx] = tile[tx][r];
  }
}

// ------------------------------------------------------------- 128x256 GEMM (B^T)
// Verified R9 structure. Grid (N/256, M/128); 512 thr = 8 waves (2M x 4N);
// per-wave 64x64 = acc[4][4]. K-tile BK=64 = 2 halves; per half: A [128][32]
// (8KB) + B [256][32] (16KB). 2-tile dbuf = 96KB. Groups (3 loads/thread)
// issued 3 phases ahead; counted vmcnt(6)/phase. XOR swizzle
// byte ^= ((row&8)<<1)|((row&4)<<3) on reads; gload_lds dest linear, source
// k-chunk pre-inverse-swizzled (same involution).
// MODE 2 (QKV): bias; Q cols (<1024) x CEXP; V cols (>=2048) -> vT scatter.
// MODE 1 (out-proj): bias; dyn f32/bf16 store per flag.
template <int MODE>
__global__ __launch_bounds__(512) void gemm_v2(
    const bf16_t* __restrict__ A, const bf16_t* __restrict__ Bt,
    const float* __restrict__ bias, void* __restrict__ Cout,
    int M, int N, int K, bf16_t* __restrict__ vT,
    const int* __restrict__ flag) {
  __shared__ __align__(16) char smem[98304];
  char* lds = smem;
  const int t = threadIdx.x;
  const int wave = t >> 6, lane = t & 63;
  const int quad = lane >> 4, l16 = lane & 15;
  const int wr = wave >> 2, wc = wave & 3;     // 2M x 4N
  const int nwg = gridDim.x * gridDim.y;       // %8==0 for our grids
  const int lin = blockIdx.y * gridDim.x + blockIdx.x;
  const int cpx = nwg >> 3;
  const int swzb = (lin & 7) * cpx + (lin >> 3);
  const int bx = swzb % gridDim.x, by = swzb / gridDim.x;
  const int bM = by * 128, bN = bx * 256;

  const int srow = t >> 2;
  const int xr = ((srow >> 3) & 1) | (((srow >> 2) & 1) << 1);
  const int skl = ((t ^ xr) & 3) * 8;
  const size_t offA = (size_t)(bM + srow) * K + skl;
  const size_t offB = (size_t)(bN + srow) * K + skl;
  const size_t offB2 = offB + (size_t)128 * K;

#define STG(g) do {                                                            \
    const int tile_ = (g) >> 1, half_ = (g) & 1;                               \
    const int kk_ = tile_ * 64 + half_ * 32;                                   \
    char* base_ = lds + ((tile_ & 1) ? 49152 : 0);                             \
    async_ld16(base_ + half_ * 8192 + t * 16, A + offA + kk_);                 \
    async_ld16(base_ + 16384 + half_ * 16384 + t * 16, Bt + offB + kk_);       \
    async_ld16(base_ + 16384 + half_ * 16384 + 8192 + t * 16,                  \
               Bt + offB2 + kk_); } while (0)

  int aoff[4], boff[4];
#pragma unroll
  for (int mf = 0; mf < 4; ++mf) {
    int r = wr * 64 + mf * 16 + l16;           // 0..127
    aoff[mf] = ((r << 6) + (quad << 4)) ^ (((r & 8) << 1) | ((r & 4) << 3));
  }
#pragma unroll
  for (int nf = 0; nf < 4; ++nf) {
    int r = wc * 64 + nf * 16 + l16;           // 0..255
    boff[nf] = ((r << 6) + (quad << 4)) ^ (((r & 8) << 1) | ((r & 4) << 3));
  }

  f32x4 acc[4][4] = {};
  const int NT = K >> 6;                       // 16 tiles, 32 groups

  STG(0); STG(1); STG(2);
  asm volatile("s_waitcnt vmcnt(6)" ::: "memory");
  __builtin_amdgcn_s_barrier();
  asm volatile("" ::: "memory");

#define PHASE(T, h) do {                                                       \
    const int bufo_ = ((T) & 1) * 49152;                                       \
    bf16x8 af[4], bf[4];                                                       \
    _Pragma("unroll") for (int i_ = 0; i_ < 4; ++i_)                           \
      af[i_] = *(const bf16x8*)(lds + bufo_ + (h) * 8192 + aoff[i_]);          \
    _Pragma("unroll") for (int j_ = 0; j_ < 4; ++j_)                           \
      bf[j_] = *(const bf16x8*)(lds + bufo_ + 16384 + (h) * 16384 + boff[j_]); \
    const int n_ = 2 * (T) + (h);                                              \
    if (n_ + 3 < 2 * NT) {                                                     \
      STG(n_ + 3);                                                             \
      asm volatile("s_waitcnt vmcnt(6)" ::: "memory");                         \
    } else if (n_ == 2 * NT - 3) {                                             \
      asm volatile("s_waitcnt vmcnt(3)" ::: "memory");                         \
    } else if (n_ == 2 * NT - 2) {                                             \
      asm volatile("s_waitcnt vmcnt(0)" ::: "memory");                         \
    }                                                                          \
    __builtin_amdgcn_s_barrier();                                              \
    asm volatile("" ::: "memory");                                             \
    __builtin_amdgcn_s_setprio(1);                                             \
    _Pragma("unroll") for (int i_ = 0; i_ < 4; ++i_)                           \
      { _Pragma("unroll") for (int j_ = 0; j_ < 4; ++j_)                       \
        acc[i_][j_] = __builtin_amdgcn_mfma_f32_16x16x32_bf16(                 \
            af[i_], bf[j_], acc[i_][j_], 0, 0, 0); }                           \
    __builtin_amdgcn_s_setprio(0);                                             \
    asm volatile("" ::: "memory");                                             \
    __builtin_amdgcn_s_barrier(); } while (0)

  for (int T = 0; T < NT; ++T) {
    PHASE(T, 0);
    PHASE(T, 1);
  }

  const bool f32out = (MODE == 1) && flag[0];
#pragma unroll
  for (int nf = 0; nf < 4; ++nf) {
    int col = bN + wc * 64 + nf * 16 + l16;
    float bv = bias[col];
#pragma unroll
    for (int mf = 0; mf < 4; ++mf) {
      int row0 = bM + wr * 64 + mf * 16 + quad * 4;
      if (MODE == 2 && col >= 2048) {
        int hh = (col - 2048) >> 6, dd = (col - 2048) & 63;
        bf16_t o4[4];
        for (int r = 0; r < 4; ++r) o4[r] = (bf16_t)(acc[mf][nf][r] + bv);
        size_t dst = ((((size_t)(row0 >> 11) * NH + hh) * HD + dd) << 11) | (row0 & 2047);
        *(uint2*)&vT[dst] = *(uint2*)o4;
      } else if (MODE == 2) {
        float scale = (col < 1024) ? CEXP : 1.0f;
        for (int r = 0; r < 4; ++r)
          ((bf16_t*)Cout)[(size_t)(row0 + r) * N + col] =
              (bf16_t)((acc[mf][nf][r] + bv) * scale);
      } else {
        for (int r = 0; r < 4; ++r) {
          float v = acc[mf][nf][r] + bv;
          if (f32out) ((float*)Cout)[(size_t)(row0 + r) * N + col] = v;
          else        ((bf16_t*)Cout)[(size_t)(row0 + r) * N + col] = (bf16_t)v;
        }
      }
    }
  }
#undef STG
#undef PHASE
}

// ------------------------------------------------------------- flash attention v12
// (verified 90.3us R7/R9.) Grid (64, 8) x 512 thr; KVBLK=128; 64KB LDS dbuf;
// wave owns 32 q (2 subtiles). S^T via 16x16x32 (Q pre-scaled by CEXP); exp2
// direct; PV via 16x16x16 from regs; softmax denominator on the MFMA pipe:
// lsum = MFMA(ones, P, lsum), epilogue reads lsum[0] (no shuffles).
// Mfma 55 + VALU 38 ~ issue-saturated; near this structure's ceiling.
__global__ __launch_bounds__(512) void attention_v12(
    const bf16_t* __restrict__ qkv, const bf16_t* __restrict__ vT,
    bf16_t* __restrict__ attn) {
  const int t = threadIdx.x;
  const int wave = t >> 6, lane = t & 63;           // wave 0..7
  const int quad = lane >> 4, l16 = lane & 15;
  const int bh = blockIdx.x, b = bh >> 4, h = bh & 15;
  const int qw = blockIdx.y * 256 + wave * 32;

  __shared__ bf16_t Kt[2][128 * 64];   // [key][d], 16B-chunk XOR swizzle by key&7
  __shared__ bf16_t Vt[2][64 * 128];   // [d][key], 16B-chunk XOR swizzle by d&15

  const bf16_t* qglob = qkv + (size_t)b * SEQ * 3072 + h * 64;
  const bf16_t* kglob = qglob + 1024;
  const bf16_t* vglob = vT + (size_t)bh * HD * SEQ;

  bf16x8 qf[2][2];
  for (int s = 0; s < 2; ++s) {
    const bf16_t* qrow = qglob + (size_t)(qw + s * 16 + l16) * 3072 + quad * 8;
    qf[s][0] = *(const bf16x8*)qrow;
    qf[s][1] = *(const bf16x8*)(qrow + 32);
  }

  f32x4 accO[2][4] = {};
  f32x4 lsum[2] = {};                       // denominator via ones-MFMA
  const short4v ones4 = {(short)0x3F80, (short)0x3F80, (short)0x3F80, (short)0x3F80};

  const int kRow = lane >> 3, kSlot = lane & 7;
  const int vRow = lane >> 4, vSlot = lane & 15;

  auto stageKV = [&](int buf, int kt) {
    for (int j = 0; j < 2; ++j) {   // K: wave stages keys [wave*16, +16)
      int keyl = wave * 16 + j * 8 + kRow;
      int gc = kSlot ^ (keyl & 7);
      async_ld16((char*)Kt[buf] + (wave * 16 + j * 8) * 128,
                 kglob + (size_t)(kt + keyl) * 3072 + gc * 8);
    }
    for (int j = 0; j < 2; ++j) {   // V: wave stages d [wave*8, +8)
      int d = wave * 8 + j * 4 + vRow;
      int gc = vSlot ^ (d & 15);
      async_ld16((char*)Vt[buf] + (wave * 8 + j * 4) * 256,
                 vglob + (size_t)d * SEQ + kt + gc * 8);
    }
  };

  stageKV(0, 0);

  for (int ti = 0; ti < SEQ / 128; ++ti) {
    const int buf = ti & 1;
    __syncthreads();                       // drain this tile's DMA + publish
    if (ti + 1 < SEQ / 128) stageKV(buf ^ 1, (ti + 1) * 128);

    const bf16_t* KtB = Kt[buf];
    const bf16_t* VtB = Vt[buf];

    for (int kb = 0; kb < 8; ++kb) {
      const bf16_t* kr = &KtB[(kb * 16 + l16) * 64];
      bf16x8 kf0 = *(const bf16x8*)(kr + ((quad ^ (l16 & 7)) * 8));
      bf16x8 kf1 = *(const bf16x8*)(kr + (((4 + quad) ^ (l16 & 7)) * 8));

      short4v pB[2];
      for (int s = 0; s < 2; ++s) {
        f32x4 z = {0.f, 0.f, 0.f, 0.f};
        f32x4 st = __builtin_amdgcn_mfma_f32_16x16x32_bf16(kf0, qf[s][0], z, 0, 0, 0);
        st = __builtin_amdgcn_mfma_f32_16x16x32_bf16(kf1, qf[s][1], st, 0, 0, 0);
        union { bf16_t hh[4]; short4v s4; } u;
        for (int r = 0; r < 4; ++r) {
          float p = __builtin_amdgcn_exp2f(st[r]);   // Q pre-scaled by CEXP
          u.hh[r] = (bf16_t)p;
        }
        pB[s] = u.s4;
        lsum[s] = MFMA_PV(ones4, pB[s], lsum[s]);    // denominator on MFMA pipe
      }

      const int chunkbase = kb * 2 + (quad >> 1);
      const int coff = (quad & 1) * 4;
      for (int db = 0; db < 4; ++db) {
        short4v vf = *(const short4v*)&VtB[(db * 16 + l16) * 128 +
                                           ((chunkbase ^ l16) * 8) + coff];
        for (int s = 0; s < 2; ++s)
          accO[s][db] = MFMA_PV(vf, pB[s], accO[s][db]);
      }
    }
  }

  for (int s = 0; s < 2; ++s) {
    float inv = 1.f / lsum[s][0];          // all rows identical; no shuffles
    size_t tok = (size_t)b * SEQ + qw + s * 16 + l16;
    for (int db = 0; db < 4; ++db) {
      bf16_t o4[4];
      for (int r = 0; r < 4; ++r) o4[r] = (bf16_t)(accO[s][db][r] * inv);
      *(uint2*)&attn[tok * DMODEL + h * HD + db * 16 + quad * 4] = *(uint2*)o4;
    }
  }
}

// ------------------------------------------------------------- launch
extern "C" void kernel_launch(void* const* d_in, const int* in_sizes, int n_in,
                              void* d_out, int out_size, void* d_ws, size_t ws_size,
                              hipStream_t stream) {
  const void* x     = d_in[0];
  const void* w_qkv = d_in[1];
  const void* b_qkv = d_in[2];
  const void* w_out = d_in[3];
  const void* b_out = d_in[4];

  char* ws = (char*)d_ws;
  int*    flag  = (int*)ws;                                    // @0
  bf16_t* wqkvT = (bf16_t*)(ws + 4096);                        // 6.0 MB
  bf16_t* woutT = (bf16_t*)(ws + 6295552);                     // 2.0 MB
  float*  bqkvf = (float*)(ws + 8392704);
  float*  boutf = (float*)(ws + 8404992);
  bf16_t* qkv   = (bf16_t*)(ws + 8409088);                     // 8192x3072 bf16 (50.3 MB)
  bf16_t* xb    = (bf16_t*)(ws + 58740736);                    // 16.8 MB
  bf16_t* attn  = xb;                                          // alias (xb dead after gemm1)
  bf16_t* vTbuf = (bf16_t*)(ws + 75517952);                    // 16.8 MB -> end ~92.3 MB

  sniff_dtype<<<1, 256, 0, stream>>>((const uint4*)x, flag, b_qkv, b_out,
                                     bqkvf, boutf);

  conv_and_transpose<<<8192, 256, 0, stream>>>(x, xb, w_qkv, wqkvT, w_out, woutT,
                                               flag);

  gemm_v2<2><<<dim3(12, 64), 512, 0, stream>>>(
      xb, wqkvT, bqkvf, qkv, NTOK, 3072, 1024, vTbuf, flag);

  attention_v12<<<dim3(BATCH * NH, SEQ / 256), 512, 0, stream>>>(qkv, vTbuf, attn);

  gemm_v2<1><<<dim3(4, 64), 512, 0, stream>>>(
      attn, woutT, boutf, d_out, NTOK, 1024, 1024, nullptr, flag);
}